// Round 15
// baseline (762.545 us; speedup 1.0000x reference)
//
#include <hip/hip_runtime.h>
#include <hip/hip_cooperative_groups.h>

namespace cg = cooperative_groups;

typedef __attribute__((ext_vector_type(8))) short short8;
typedef __attribute__((ext_vector_type(4))) float floatx4;
typedef __attribute__((ext_vector_type(4))) unsigned int uint32x4;

#define NROWS 32768L          // padded row count (real pair rows = 32767)
#define NVALID 32767L
#define HGDIM 1024

__device__ __forceinline__ unsigned short f2bf_rne(float f) {
    union { float f; unsigned u; } v; v.f = f;
    unsigned r = v.u + 0x7fffu + ((v.u >> 16) & 1u);
    return (unsigned short)(r >> 16);
}

__device__ __forceinline__ void gload_lds16(const void* g, void* l) {
    __builtin_amdgcn_global_load_lds(
        (const __attribute__((address_space(1))) void*)g,
        (__attribute__((address_space(3))) void*)l,
        16, 0, 0);
}

// ================== shared GEMM body (round-14 proven schedule) ==================
#define SBAR() __builtin_amdgcn_sched_barrier(0)

#define U_PRE() do { SBAR(); \
    asm volatile("s_waitcnt lgkmcnt(0)" ::: "memory"); SBAR(); \
    __builtin_amdgcn_s_setprio(1); } while (0)

#define U_POST() do { __builtin_amdgcn_s_setprio(0); SBAR(); \
    asm volatile("s_waitcnt vmcnt(2)" ::: "memory"); SBAR(); \
    __builtin_amdgcn_s_barrier(); } while (0)

#define STAGE(buf, region, T) do { \
    if ((region) >= 2) { \
        const unsigned short* _g = gA + (long)(((region) & 1) * 128) * lda + (long)(T) * 64; \
        char* _d = (char*)&lds[buf][0][((region) & 1) * 128][0] + t * 16; \
        gload_lds16(_g, _d); \
        gload_lds16(_g + 64L * lda, _d + 8192); \
    } else { \
        const unsigned short* _g = gB + (long)(((region) & 1) * 128) * ldb + (long)(T) * 64; \
        char* _d = (char*)&lds[buf][1][((region) & 1) * 128][0] + t * 16; \
        gload_lds16(_g, _d); \
        gload_lds16(_g + 64L * ldb, _d + 8192); \
    } } while (0)

#define LDA4(dst, buf, mbase, ks) do { _Pragma("unroll") for (int _q = 0; _q < 4; ++_q) \
    dst[_q] = *(const short8*)((const char*)&lds[buf][0][arowb + ((mbase) + _q) * 16][0] + ((ks) ? cb1 : cb0)); } while (0)

#define LDB4(dst, buf, ks) do { _Pragma("unroll") for (int _q = 0; _q < 4; ++_q) \
    dst[_q] = *(const short8*)((const char*)&lds[buf][1][browb + _q * 16][0] + ((ks) ? cb1 : cb0)); } while (0)

#define MFMA16(AF, BF, MO) do { _Pragma("unroll") for (int _mf = 0; _mf < 4; ++_mf) { \
    _Pragma("unroll") for (int _nf = 0; _nf < 4; ++_nf) \
        acc[(MO) + _mf][_nf] = __builtin_amdgcn_mfma_f32_16x16x32_bf16(AF[_mf], BF[_nf], acc[(MO) + _mf][_nf], 0, 0, 0); } } while (0)

template<int COLSUM>
__device__ __forceinline__ void gemm_body(
    unsigned short (&lds)[2][2][256][64],
    const unsigned short* __restrict__ A, int lda,
    const unsigned short* __restrict__ Bt, int ldb,
    const float* __restrict__ bias, int K,
    unsigned short* __restrict__ Hout, float* __restrict__ emb,
    long row0g, long m0, int n0, long nvalid, int t)
{
    __syncthreads();   // protect LDS reuse across sequential calls

    const int srow = t >> 3;
    const int ssc = (t & 7) ^ (srow & 7);
    const unsigned short* gA = A + (m0 + srow) * (long)lda + ssc * 8;
    const unsigned short* gB = Bt + ((long)n0 + srow) * (long)ldb + ssc * 8;

    const int lane = t & 63;
    const int wv = t >> 6;
    const int wm = wv >> 2, wn = wv & 3;
    const int arowb = wm * 128 + (lane & 15);
    const int browb = wn * 64 + (lane & 15);
    const int c0x = (lane >> 4) ^ (lane & 7);
    const int cb0 = c0x * 16;
    const int cb1 = (c0x ^ 4) * 16;

    floatx4 acc[8][4] = {};
    const int NT = K >> 6;
    const int NI = NT >> 1;

    short8 bE0[4], bE1[4], bO0[4], bO1[4];
    short8 aE0[4], aE1[4], aE2[4], aE3[4], aO0[4], aO1[4], aO2[4], aO3[4];

    STAGE(0, 0, 0); STAGE(0, 1, 0); STAGE(0, 2, 0); STAGE(0, 3, 0);
    STAGE(1, 0, 1); STAGE(1, 1, 1);
    asm volatile("s_waitcnt vmcnt(4)" ::: "memory");
    SBAR();
    __builtin_amdgcn_s_barrier();
    SBAR();
    LDB4(bE0, 0, 0); LDA4(aE0, 0, 0, 0);

    for (int i = 0; i < NI; ++i) {
        const int O = 2 * i + 1;
        int N2 = 2 * i + 2; if (N2 >= NT) N2 = 0;
        int P2 = 2 * i + 3; if (P2 >= NT) P2 = 1;

        U_PRE();
        LDA4(aE1, 0, 4, 0);
        STAGE(1, 2, O);
        MFMA16(aE0, bE0, 0);
        U_POST();
        U_PRE();
        LDB4(bE1, 0, 1); LDA4(aE2, 0, 0, 1);
        STAGE(1, 3, O);
        MFMA16(aE1, bE0, 4);
        U_POST();
        U_PRE();
        LDA4(aE3, 0, 4, 1);
        STAGE(0, 0, N2);
        MFMA16(aE2, bE1, 0);
        U_POST();
        U_PRE();
        LDB4(bO0, 1, 0); LDA4(aO0, 1, 0, 0);
        STAGE(0, 1, N2);
        MFMA16(aE3, bE1, 4);
        U_POST();
        U_PRE();
        LDA4(aO1, 1, 4, 0);
        STAGE(0, 2, N2);
        MFMA16(aO0, bO0, 0);
        U_POST();
        U_PRE();
        LDB4(bO1, 1, 1); LDA4(aO2, 1, 0, 1);
        STAGE(0, 3, N2);
        MFMA16(aO1, bO0, 4);
        U_POST();
        U_PRE();
        LDA4(aO3, 1, 4, 1);
        STAGE(1, 0, P2);
        MFMA16(aO2, bO1, 0);
        U_POST();
        U_PRE();
        LDB4(bE0, 0, 0); LDA4(aE0, 0, 0, 0);
        STAGE(1, 1, P2);
        MFMA16(aO3, bO1, 4);
        U_POST();
    }
    asm volatile("s_waitcnt vmcnt(0) lgkmcnt(0)" ::: "memory");
    SBAR();
    __builtin_amdgcn_s_barrier();

    if (COLSUM == 0) {
        char* slb = (char*)&lds[0][0][0][0];
        #pragma unroll
        for (int nf = 0; nf < 4; ++nf) {
            int ncol = wn * 64 + nf * 16 + (lane & 15);
            float bv = bias[n0 + ncol];
            #pragma unroll
            for (int mf = 0; mf < 8; ++mf) {
                int rbase = wm * 128 + mf * 16 + ((lane >> 4) << 2);
                #pragma unroll
                for (int j = 0; j < 4; ++j) {
                    int row = rbase + j;
                    float v = fmaxf(acc[mf][nf][j] + bv, 0.f);
                    int byte = row * 512 + ((ncol * 2) ^ ((row & 7) << 4));
                    *(unsigned short*)(slb + byte) = f2bf_rne(v);
                }
            }
        }
        __syncthreads();
        {
            int rsub = t >> 5;
            int cb = (t & 31) * 16;
            #pragma unroll
            for (int i2 = 0; i2 < 16; ++i2) {
                int row = i2 * 16 + rsub;
                const char* src = slb + row * 512 + (cb ^ ((row & 7) << 4));
                uint32x4 v = *(const uint32x4*)src;
                char* dst = (char*)Hout + ((size_t)(m0 + row) * HGDIM + n0) * 2 + cb;
                *(uint32x4*)dst = v;
            }
        }
    } else {
        #pragma unroll
        for (int nf = 0; nf < 4; ++nf) {
            int ncol = n0 + wn * 64 + nf * 16 + (lane & 15);
            float bv = bias[ncol];
            float cs = 0.f;
            #pragma unroll
            for (int mf = 0; mf < 8; ++mf) {
                long rbase = row0g + m0 + wm * 128 + mf * 16 + ((lane >> 4) << 2);
                #pragma unroll
                for (int j = 0; j < 4; ++j) {
                    float v = fmaxf(acc[mf][nf][j] + bv, 0.f);
                    if (rbase + j < nvalid) cs += v;
                }
            }
            cs += __shfl_xor(cs, 16);
            cs += __shfl_xor(cs, 32);
            if ((lane >> 4) == 0) atomicAdd(&emb[ncol], cs);
        }
    }
}

// ================== fused cooperative kernel ==================
struct RNParams {
    const float *x, *q, *gW0, *gb0, *gW1, *gb1, *gW2, *gb2;
    const float *fW0, *fb0, *fW1, *fb1, *fW2, *fb2;
    unsigned short *xb, *w0t, *w1t, *w2t;
    float *c0, *emb, *e1, *e2;
    unsigned short *H0, *H1;
    float *outp;
};

__device__ __forceinline__ void fc_phase(bool relu_in, const float* in, const float* W,
                                         const float* bias, float* out, int N, int ky,
                                         int t, int bid, float* sbuf) {
    int nx = N >> 8;
    int njobs = nx * ky;
    bool act = bid < njobs;
    int bx = 0, by = 0;
    if (act) { bx = bid % nx; by = bid / nx; }
    if (act && t < 128) {
        float v = in[by * 128 + t];
        if (relu_in) v = fmaxf(v, 0.f);
        sbuf[t] = v;
    }
    __syncthreads();
    if (act && t < 256) {
        int j = bx * 256 + t;
        float a = (by == 0) ? bias[j] : 0.f;
        #pragma unroll 4
        for (int k = 0; k < 128; ++k)
            a += sbuf[k] * W[(size_t)(by * 128 + k) * N + j];
        atomicAdd(&out[j], a);
    }
    __syncthreads();
}

__global__ __launch_bounds__(512, 2) void fused_rn(RNParams p) {
    __shared__ alignas(16) unsigned short lds[2][2][256][64];   // 128 KiB
    cg::grid_group grid = cg::this_grid();
    const int bid = blockIdx.x, t = threadIdx.x;

    // ---- phase 0: prep (cvt + transposes + c0 + zero) ----
    {
        long ntot4 = (NROWS + 1) * 64;
        long nx = NROWS * 256;
        for (long i = (long)bid * 512 + t; i < ntot4; i += 131072) {
            long i4 = i * 4;
            float4 v = make_float4(0.f, 0.f, 0.f, 0.f);
            if (i4 < nx) v = *(const float4*)(p.x + i4);
            ushort4 o;
            o.x = f2bf_rne(v.x); o.y = f2bf_rne(v.y);
            o.z = f2bf_rne(v.z); o.w = f2bf_rne(v.w);
            *(ushort4*)(p.xb + i4) = o;
        }
    }
    {
        float (*tiles)[32][33] = (float (*)[32][33])((void*)lds);
        int half = t >> 8, ht = t & 255;
        int tx = ht & 31, ty = ht >> 5;
        // 2560 jobs = 512 half-blocks x 5 iterations exactly -> uniform syncs
        for (int job = bid * 2 + half; job < 2560; job += 512) {
            const float* W; unsigned short* Wt; int K, N; int jj = job;
            if (jj < 512)       {             W = p.gW0; Wt = p.w0t; K = 512;  N = 1024; }
            else if (jj < 1536) { jj -= 512;  W = p.gW1; Wt = p.w1t; K = 1024; N = 1024; }
            else                { jj -= 1536; W = p.gW2; Wt = p.w2t; K = 1024; N = 1024; }
            int bx = jj & 31, by = jj >> 5;
            int nb2 = bx * 32, kb = by * 32;
            #pragma unroll
            for (int i = 0; i < 32; i += 8)
                tiles[half][ty + i][tx] = W[(size_t)(kb + ty + i) * N + (nb2 + tx)];
            __syncthreads();
            #pragma unroll
            for (int i = 0; i < 32; i += 8)
                Wt[(size_t)(nb2 + ty + i) * K + (kb + tx)] = f2bf_rne(tiles[half][tx][ty + i]);
            __syncthreads();
        }
    }
    {
        float* qs = (float*)lds;
        if (bid < 4 && t < 256) qs[t] = p.q[t];
        __syncthreads();
        if (bid < 4 && t < 256) {
            int j = bid * 256 + t;
            float a = p.gb0[j];
            #pragma unroll 4
            for (int k = 0; k < 256; ++k)
                a += qs[k] * p.gW0[(size_t)(512 + k) * 1024 + j];
            p.c0[j] = a;
        } else if (bid == 4) {
            for (int i2 = t; i2 < 1024; i2 += 512) { p.emb[i2] = 0.f; p.e1[i2] = 0.f; p.e2[i2] = 0.f; }
            if (t < 256) p.outp[t] = 0.f;
        }
    }
    __threadfence();
    grid.sync();

    // tile mapping: 256 blocks, 2 tiles each; XCD swizzle keeps A-panel sharers co-XCD
    int swz = (bid & 7) * 32 + (bid >> 3);
    const int mbB = swz >> 2, nb = swz & 3;
    const long m0a = (long)mbB * 512;
    const int n0 = nb * 256;

    // ---- phase 1: H0 = relu(x[:-1]W0a + x[1:]W0b + c0) ----
    #pragma clang loop unroll(disable)
    for (int s = 0; s < 2; ++s)
        gemm_body<0>(lds, p.xb, 256, p.w0t, 512, p.c0, 512, p.H0, nullptr,
                     0, m0a + s * 256, n0, 0, t);
    __threadfence();
    grid.sync();

    // ---- phase 2: H1 = relu(H0 @ W1 + b1) ----
    #pragma clang loop unroll(disable)
    for (int s = 0; s < 2; ++s)
        gemm_body<0>(lds, p.H0, 1024, p.w1t, 1024, p.gb1, 1024, p.H1, nullptr,
                     0, m0a + s * 256, n0, 0, t);
    __threadfence();
    grid.sync();

    // ---- phase 3: emb += colsum(relu(H1 @ W2 + b2)) ----
    #pragma clang loop unroll(disable)
    for (int s = 0; s < 2; ++s)
        gemm_body<1>(lds, p.H1, 1024, p.w2t, 1024, p.gb2, 1024, nullptr, p.emb,
                     0, m0a + s * 256, n0, NVALID, t);
    __threadfence();
    grid.sync();

    // ---- phases 4-6: f-MLP ----
    fc_phase(false, p.emb, p.fW0, p.fb0, p.e1, 1024, 8, t, bid, (float*)lds);
    __threadfence();
    grid.sync();
    fc_phase(true, p.e1, p.fW1, p.fb1, p.e2, 512, 8, t, bid, (float*)lds);
    __threadfence();
    grid.sync();
    fc_phase(true, p.e2, p.fW2, p.fb2, p.outp, 256, 4, t, bid, (float*)lds);
}

// ================== fallback multi-kernel path (round-14) ==================
#define NB_CVT 8193
#define NB_T0  512
#define NB_T1  1024
#define NB_T2  1024
#define NB_C0  4

__global__ void prep(const float* __restrict__ x, unsigned short* __restrict__ xb,
                     const float* __restrict__ gW0, unsigned short* __restrict__ w0t,
                     const float* __restrict__ gW1, unsigned short* __restrict__ w1t,
                     const float* __restrict__ gW2, unsigned short* __restrict__ w2t,
                     const float* __restrict__ q, const float* __restrict__ gb0,
                     float* __restrict__ c0, float* __restrict__ emb,
                     float* __restrict__ e1, float* __restrict__ e2,
                     float* __restrict__ out) {
    __shared__ float smem[1056];
    int b = blockIdx.x, tid = threadIdx.x;
    if (b < NB_CVT) {
        long i = (long)b * 256 + tid;
        long ntot4 = (NROWS + 1) * 64;
        if (i < ntot4) {
            long i4 = i * 4, nx = NROWS * 256;
            float4 v = make_float4(0.f, 0.f, 0.f, 0.f);
            if (i4 < nx) v = *(const float4*)(x + i4);
            ushort4 o;
            o.x = f2bf_rne(v.x); o.y = f2bf_rne(v.y);
            o.z = f2bf_rne(v.z); o.w = f2bf_rne(v.w);
            *(ushort4*)(xb + i4) = o;
        }
        return;
    }
    b -= NB_CVT;
    const float* W; unsigned short* Wt; int K, N;
    if (b < NB_T0)                  { W = gW0; Wt = w0t; K = 512;  N = 1024; }
    else if (b < NB_T0 + NB_T1)     { b -= NB_T0; W = gW1; Wt = w1t; K = 1024; N = 1024; }
    else if (b < NB_T0 + NB_T1 + NB_T2) { b -= NB_T0 + NB_T1; W = gW2; Wt = w2t; K = 1024; N = 1024; }
    else if (b < NB_T0 + NB_T1 + NB_T2 + NB_C0) {
        b -= NB_T0 + NB_T1 + NB_T2;
        int j = b * 256 + tid;
        smem[tid] = q[tid];
        __syncthreads();
        float a = gb0[j];
        #pragma unroll 4
        for (int k = 0; k < 256; ++k)
            a += smem[k] * gW0[(size_t)(512 + k) * 1024 + j];
        c0[j] = a;
        return;
    } else {
        for (int i = tid; i < 1024; i += 256) { emb[i] = 0.f; e1[i] = 0.f; e2[i] = 0.f; }
        if (tid < 256) out[tid] = 0.f;
        return;
    }
    int bx = b & 31, by = b >> 5;
    float (*tile)[33] = (float(*)[33])smem;
    int tx = tid & 31, ty = tid >> 5;
    int nb2 = bx * 32, kb = by * 32;
    #pragma unroll
    for (int i = 0; i < 32; i += 8)
        tile[ty + i][tx] = W[(size_t)(kb + ty + i) * N + (nb2 + tx)];
    __syncthreads();
    #pragma unroll
    for (int i = 0; i < 32; i += 8)
        Wt[(size_t)(nb2 + ty + i) * K + (kb + tx)] = f2bf_rne(tile[tx][ty + i]);
}

template<bool RELU_IN>
__global__ void fc_partial(const float* __restrict__ in, const float* __restrict__ W,
                           const float* __restrict__ bias, float* __restrict__ out,
                           int N) {
    __shared__ float s_in[128];
    int j = blockIdx.x * 256 + threadIdx.x;
    int k0 = blockIdx.y * 128;
    if (threadIdx.x < 128) {
        float v = in[k0 + threadIdx.x];
        if (RELU_IN) v = fmaxf(v, 0.f);
        s_in[threadIdx.x] = v;
    }
    __syncthreads();
    float acc = (blockIdx.y == 0) ? bias[j] : 0.f;
    #pragma unroll 4
    for (int k = 0; k < 128; ++k)
        acc += s_in[k] * W[(size_t)(k0 + k) * N + j];
    atomicAdd(&out[j], acc);
}

template<int COLSUM>
__global__ __launch_bounds__(512, 2)
void gemm_k(const unsigned short* __restrict__ A, int lda,
            const unsigned short* __restrict__ Bt, int ldb,
            const float* __restrict__ bias, int K,
            unsigned short* __restrict__ Hout, float* __restrict__ emb,
            long row0g, long nvalid) {
    __shared__ alignas(16) unsigned short lds[2][2][256][64];
    int nwg = gridDim.x, bid = blockIdx.x, swz;
    if ((nwg & 7) == 0) { int cpx = nwg >> 3; swz = (bid & 7) * cpx + (bid >> 3); }
    else swz = bid;
    int mb = swz >> 2, nb = swz & 3;
    gemm_body<COLSUM>(lds, A, lda, Bt, ldb, bias, K, Hout, emb,
                      row0g, (long)mb * 256, nb * 256, nvalid, threadIdx.x);
}

extern "C" void kernel_launch(void* const* d_in, const int* in_sizes, int n_in,
                              void* d_out, int out_size, void* d_ws, size_t ws_size,
                              hipStream_t stream) {
    const float* x   = (const float*)d_in[0];
    const float* q   = (const float*)d_in[1];
    const float* gW0 = (const float*)d_in[2];
    const float* gb0 = (const float*)d_in[3];
    const float* gW1 = (const float*)d_in[4];
    const float* gb1 = (const float*)d_in[5];
    const float* gW2 = (const float*)d_in[6];
    const float* gb2 = (const float*)d_in[7];
    const float* fW0 = (const float*)d_in[8];
    const float* fb0 = (const float*)d_in[9];
    const float* fW1 = (const float*)d_in[10];
    const float* fb1 = (const float*)d_in[11];
    const float* fW2 = (const float*)d_in[12];
    const float* fb2 = (const float*)d_in[13];
    float* out = (float*)d_out;

    char* ws = (char*)d_ws;
    size_t off = 0;
    auto alloc = [&](size_t bytes) -> char* {
        char* p = ws + off;
        off += (bytes + 255) & ~(size_t)255;
        return p;
    };
    unsigned short* xb  = (unsigned short*)alloc((NROWS + 1) * 256 * 2);  // +1 zero row
    unsigned short* w0t = (unsigned short*)alloc((size_t)1024 * 512 * 2);
    unsigned short* w1t = (unsigned short*)alloc((size_t)1024 * 1024 * 2);
    unsigned short* w2t = (unsigned short*)alloc((size_t)1024 * 1024 * 2);
    float* c0  = (float*)alloc(4096);
    float* emb = (float*)alloc(4096);
    float* e1  = (float*)alloc(4096);
    float* e2  = (float*)alloc(4096);
    size_t fixed = off;
    size_t avail = (ws_size > fixed) ? ws_size - fixed : 0;
    long CR = (long)((avail / 2) / (HGDIM * 2));
    CR = (CR / 512) * 512;
    if (CR > NROWS) CR = NROWS;
    if (CR < 512) CR = 512;
    unsigned short* H0 = (unsigned short*)alloc((size_t)CR * HGDIM * 2);
    unsigned short* H1 = (unsigned short*)alloc((size_t)CR * HGDIM * 2);

    int dev = 0;
    hipGetDevice(&dev);
    int coop = 0;
    hipDeviceGetAttribute(&coop, hipDeviceAttributeCooperativeLaunch, dev);

    if (coop && CR >= NROWS) {
        RNParams p;
        p.x = x; p.q = q; p.gW0 = gW0; p.gb0 = gb0; p.gW1 = gW1; p.gb1 = gb1;
        p.gW2 = gW2; p.gb2 = gb2; p.fW0 = fW0; p.fb0 = fb0; p.fW1 = fW1; p.fb1 = fb1;
        p.fW2 = fW2; p.fb2 = fb2; p.xb = xb; p.w0t = w0t; p.w1t = w1t; p.w2t = w2t;
        p.c0 = c0; p.emb = emb; p.e1 = e1; p.e2 = e2; p.H0 = H0; p.H1 = H1; p.outp = out;
        void* kargs[] = { (void*)&p };
        hipLaunchCooperativeKernel((const void*)fused_rn, dim3(256), dim3(512),
                                   kargs, 0, stream);
    } else {
        prep<<<dim3(NB_CVT + NB_T0 + NB_T1 + NB_T2 + NB_C0 + 1), 256, 0, stream>>>(
            x, xb, gW0, w0t, gW1, w1t, gW2, w2t, q, gb0, c0, emb, e1, e2, out);

        for (long r0 = 0; r0 < NROWS; r0 += CR) {
            long rows = NROWS - r0; if (rows > CR) rows = CR;
            int mblocks = (int)(rows / 256);
            dim3 g((unsigned)(mblocks * 4));
            gemm_k<0><<<g, 512, 0, stream>>>(xb + r0 * 256, 256, w0t, 512, c0, 512,
                                             H0, nullptr, 0, 0);
            gemm_k<0><<<g, 512, 0, stream>>>(H0, 1024, w1t, 1024, gb1, 1024,
                                             H1, nullptr, 0, 0);
            gemm_k<1><<<g, 512, 0, stream>>>(H1, 1024, w2t, 1024, gb2, 1024,
                                             nullptr, emb, r0, NVALID);
        }

        fc_partial<false><<<dim3(4, 8), 256, 0, stream>>>(emb, fW0, fb0, e1, 1024);
        fc_partial<true><<<dim3(2, 8), 256, 0, stream>>>(e1, fW1, fb1, e2, 512);
        fc_partial<true><<<dim3(1, 4), 256, 0, stream>>>(e2, fW2, fb2, out, 256);
    }
}

// Round 16
// 230.762 us; speedup vs baseline: 3.3045x; 3.3045x over previous
//
#include <hip/hip_runtime.h>

typedef __attribute__((ext_vector_type(8))) short short8;
typedef __attribute__((ext_vector_type(4))) float floatx4;
typedef __attribute__((ext_vector_type(4))) unsigned int uint32x4;

#define NROWS 32768L          // padded row count (real pair rows = 32767)
#define NVALID 32767L
#define HGDIM 1024

__device__ __forceinline__ unsigned short f2bf_rne(float f) {
    union { float f; unsigned u; } v; v.f = f;
    unsigned r = v.u + 0x7fffu + ((v.u >> 16) & 1u);
    return (unsigned short)(r >> 16);
}

__device__ __forceinline__ void gload_lds16(const void* g, void* l) {
    __builtin_amdgcn_global_load_lds(
        (const __attribute__((address_space(1))) void*)g,
        (__attribute__((address_space(3))) void*)l,
        16, 0, 0);
}

// ====== fused prep: cvt_x + 3 weight transposes + c0(direct) + zero-accums ======
#define NB_CVT 8193
#define NB_T0  512
#define NB_T1  1024
#define NB_T2  1024
#define NB_C0  4
// +1 zero block at the end

__global__ void prep(const float* __restrict__ x, unsigned short* __restrict__ xb,
                     const float* __restrict__ gW0, unsigned short* __restrict__ w0t,
                     const float* __restrict__ gW1, unsigned short* __restrict__ w1t,
                     const float* __restrict__ gW2, unsigned short* __restrict__ w2t,
                     const float* __restrict__ q, const float* __restrict__ gb0,
                     float* __restrict__ c0, float* __restrict__ emb,
                     float* __restrict__ e1, float* __restrict__ e2,
                     float* __restrict__ out) {
    __shared__ float smem[1056];
    int b = blockIdx.x, tid = threadIdx.x;
    if (b < NB_CVT) {
        long i = (long)b * 256 + tid;
        long ntot4 = (NROWS + 1) * 64;
        if (i < ntot4) {
            long i4 = i * 4, nx = NROWS * 256;
            float4 v = make_float4(0.f, 0.f, 0.f, 0.f);
            if (i4 < nx) v = *(const float4*)(x + i4);
            ushort4 o;
            o.x = f2bf_rne(v.x); o.y = f2bf_rne(v.y);
            o.z = f2bf_rne(v.z); o.w = f2bf_rne(v.w);
            *(ushort4*)(xb + i4) = o;
        }
        return;
    }
    b -= NB_CVT;
    const float* W; unsigned short* Wt; int K, N;
    if (b < NB_T0)                  { W = gW0; Wt = w0t; K = 512;  N = 1024; }
    else if (b < NB_T0 + NB_T1)     { b -= NB_T0; W = gW1; Wt = w1t; K = 1024; N = 1024; }
    else if (b < NB_T0 + NB_T1 + NB_T2) { b -= NB_T0 + NB_T1; W = gW2; Wt = w2t; K = 1024; N = 1024; }
    else if (b < NB_T0 + NB_T1 + NB_T2 + NB_C0) {
        // c0[j] = gb0[j] + sum_k q[k] * gW0[512+k][j]  -- direct write, no atomics
        b -= NB_T0 + NB_T1 + NB_T2;
        int j = b * 256 + tid;
        smem[tid] = q[tid];                 // q is 256 elements, 256 threads
        __syncthreads();
        float a = gb0[j];
        #pragma unroll 4
        for (int k = 0; k < 256; ++k)
            a += smem[k] * gW0[(size_t)(512 + k) * 1024 + j];
        c0[j] = a;
        return;
    } else {
        // zero block: emb/e1/e2 (1024 each) + out (256)
        for (int i = tid; i < 1024; i += 256) { emb[i] = 0.f; e1[i] = 0.f; e2[i] = 0.f; }
        if (tid < 256) out[tid] = 0.f;
        return;
    }
    int bx = b & 31, by = b >> 5;
    float (*tile)[33] = (float(*)[33])smem;
    int tx = tid & 31, ty = tid >> 5;
    int nb2 = bx * 32, kb = by * 32;
    #pragma unroll
    for (int i = 0; i < 32; i += 8)
        tile[ty + i][tx] = W[(size_t)(kb + ty + i) * N + (nb2 + tx)];
    __syncthreads();
    #pragma unroll
    for (int i = 0; i < 32; i += 8)
        Wt[(size_t)(nb2 + ty + i) * K + (kb + tx)] = f2bf_rne(tile[tx][ty + i]);
}

// ---- small fp32 FC partial (multi-block, atomic K-split) ----
template<bool RELU_IN>
__global__ void fc_partial(const float* __restrict__ in, const float* __restrict__ W,
                           const float* __restrict__ bias, float* __restrict__ out,
                           int N) {
    __shared__ float s_in[128];
    int j = blockIdx.x * 256 + threadIdx.x;
    int k0 = blockIdx.y * 128;
    if (threadIdx.x < 128) {
        float v = in[k0 + threadIdx.x];
        if (RELU_IN) v = fmaxf(v, 0.f);
        s_in[threadIdx.x] = v;
    }
    __syncthreads();
    float acc = (blockIdx.y == 0) ? bias[j] : 0.f;
    #pragma unroll 4
    for (int k = 0; k < 128; ++k)
        acc += s_in[k] * W[(size_t)(k0 + k) * N + j];
    atomicAdd(&out[j], acc);
}

// ================== 256x256 8-phase bf16 MFMA GEMM (single-barrier phases) =======
// Region p: { lgkmcnt(0); setprio(1); reads-for-p+1 + stage + 16 MFMA (no internal
// fences); setprio(0); vmcnt(4); s_barrier }.  ONE barrier per phase.
// Proof: min stage->first-read distance in this mapping is 3 phases; vmcnt(4) at
// end-(q+2) leaves only stages q+1,q+2 (4 loads) unproven -> stage@q proven +
// published before its first read at q+3.  WAR: restage >=2 phases + >=1 barrier
// after last read-issue (DMA flight >=400cy vs read queue <=150cy).
// C(m,n) = A(m x K) * Bt(n x K)^T.  COLSUM=0: Hout=relu(C+bias), LDS-bounce,
// nontemporal full-line stores (keep L2 clean; H lands in L3 for next GEMM).
// COLSUM=1: masked column-sum of relu(C+bias) atomicAdd into emb.

#define SBAR() __builtin_amdgcn_sched_barrier(0)

#define U_PRE() do { SBAR(); \
    asm volatile("s_waitcnt lgkmcnt(0)" ::: "memory"); SBAR(); \
    __builtin_amdgcn_s_setprio(1); } while (0)

#define U_POST() do { __builtin_amdgcn_s_setprio(0); SBAR(); \
    asm volatile("s_waitcnt vmcnt(4)" ::: "memory"); SBAR(); \
    __builtin_amdgcn_s_barrier(); } while (0)

// stage one half-tile (128 rows x 64 cols bf16 = 16KB) of tile T into buf.
// region 0: B rows 0-127, 1: B rows 128-255, 2: A rows 0-127, 3: A rows 128-255.
#define STAGE(buf, region, T) do { \
    if ((region) >= 2) { \
        const unsigned short* _g = gA + (long)(((region) & 1) * 128) * lda + (long)(T) * 64; \
        char* _d = (char*)&lds[buf][0][((region) & 1) * 128][0] + t * 16; \
        gload_lds16(_g, _d); \
        gload_lds16(_g + 64L * lda, _d + 8192); \
    } else { \
        const unsigned short* _g = gB + (long)(((region) & 1) * 128) * ldb + (long)(T) * 64; \
        char* _d = (char*)&lds[buf][1][((region) & 1) * 128][0] + t * 16; \
        gload_lds16(_g, _d); \
        gload_lds16(_g + 64L * ldb, _d + 8192); \
    } } while (0)

#define LDA4(dst, buf, mbase, ks) do { _Pragma("unroll") for (int _q = 0; _q < 4; ++_q) \
    dst[_q] = *(const short8*)((const char*)&lds[buf][0][arowb + ((mbase) + _q) * 16][0] + ((ks) ? cb1 : cb0)); } while (0)

#define LDB4(dst, buf, ks) do { _Pragma("unroll") for (int _q = 0; _q < 4; ++_q) \
    dst[_q] = *(const short8*)((const char*)&lds[buf][1][browb + _q * 16][0] + ((ks) ? cb1 : cb0)); } while (0)

#define MFMA16(AF, BF, MO) do { _Pragma("unroll") for (int _mf = 0; _mf < 4; ++_mf) { \
    _Pragma("unroll") for (int _nf = 0; _nf < 4; ++_nf) \
        acc[(MO) + _mf][_nf] = __builtin_amdgcn_mfma_f32_16x16x32_bf16(AF[_mf], BF[_nf], acc[(MO) + _mf][_nf], 0, 0, 0); } } while (0)

template<int COLSUM>
__global__ __launch_bounds__(512, 2)
void gemmV(const unsigned short* __restrict__ A, int lda,
           const unsigned short* __restrict__ Bt, int ldb,
           const float* __restrict__ bias, int K,
           unsigned short* __restrict__ Hout,
           float* __restrict__ emb, long row0g, long nvalid,
           int mblocks) {
    __shared__ alignas(16) unsigned short lds[2][2][256][64];  // 128 KiB

    const int t = threadIdx.x;        // 0..511
    // XCD-aware swizzle (bijective since nwg % 8 == 0); n-fastest within chunk
    // so the 4 blocks sharing an A panel are co-resident on one XCD.
    int nwg = gridDim.x, bid = blockIdx.x, swz;
    if ((nwg & 7) == 0) { int cpx = nwg >> 3; swz = (bid & 7) * cpx + (bid >> 3); }
    else swz = bid;
    const int mb = swz >> 2, nb = swz & 3;
    const long m0 = (long)mb * 256;
    const int n0 = nb * 256;

    // staging addresses: thread t covers (row = t>>3 within 64-row group, chunk = t&7)
    const int srow = t >> 3;
    const int ssc = (t & 7) ^ (srow & 7);             // pre-swizzled source chunk
    const unsigned short* gA = A + (m0 + srow) * (long)lda + ssc * 8;
    const unsigned short* gB = Bt + ((long)n0 + srow) * (long)ldb + ssc * 8;

    // ds_read fragment addressing
    const int lane = t & 63;
    const int wv = t >> 6;
    const int wm = wv >> 2, wn = wv & 3;              // 2 M-waves x 4 N-waves
    const int arowb = wm * 128 + (lane & 15);
    const int browb = wn * 64 + (lane & 15);
    const int c0x = (lane >> 4) ^ (lane & 7);
    const int cb0 = c0x * 16;
    const int cb1 = (c0x ^ 4) * 16;

    floatx4 acc[8][4] = {};

    const int NT = K >> 6;            // 64-wide K tiles (8 or 16; even)
    const int NI = NT >> 1;

    short8 bE0[4], bE1[4], bO0[4], bO1[4];
    short8 aE0[4], aE1[4], aE2[4], aE3[4], aO0[4], aO1[4], aO2[4], aO3[4];

    // prologue: tile0 full -> buf0; tile1 B-halves -> buf1; counted wait + barrier
    STAGE(0, 0, 0); STAGE(0, 1, 0); STAGE(0, 2, 0); STAGE(0, 3, 0);
    STAGE(1, 0, 1); STAGE(1, 1, 1);
    asm volatile("s_waitcnt vmcnt(4)" ::: "memory");   // tile0 landed; T1.B in flight
    SBAR();
    __builtin_amdgcn_s_barrier();
    SBAR();
    LDB4(bE0, 0, 0); LDA4(aE0, 0, 0, 0);               // drained by ph1's lgkm(0)

    for (int i = 0; i < NI; ++i) {
        const int O = 2 * i + 1;
        int N2 = 2 * i + 2; if (N2 >= NT) N2 = 0;      // wrap: redundant loads, safe
        int P2 = 2 * i + 3; if (P2 >= NT) P2 = 1;

        // ---- ph1 ----
        U_PRE();
        LDA4(aE1, 0, 4, 0);
        STAGE(1, 2, O);
        MFMA16(aE0, bE0, 0);
        U_POST();
        // ---- ph2 ----
        U_PRE();
        LDB4(bE1, 0, 1); LDA4(aE2, 0, 0, 1);
        STAGE(1, 3, O);
        MFMA16(aE1, bE0, 4);
        U_POST();
        // ---- ph3 ----
        U_PRE();
        LDA4(aE3, 0, 4, 1);
        STAGE(0, 0, N2);
        MFMA16(aE2, bE1, 0);
        U_POST();
        // ---- ph4 ----
        U_PRE();
        LDB4(bO0, 1, 0); LDA4(aO0, 1, 0, 0);
        STAGE(0, 1, N2);
        MFMA16(aE3, bE1, 4);
        U_POST();
        // ---- ph5 ----
        U_PRE();
        LDA4(aO1, 1, 4, 0);
        STAGE(0, 2, N2);
        MFMA16(aO0, bO0, 0);
        U_POST();
        // ---- ph6 ----
        U_PRE();
        LDB4(bO1, 1, 1); LDA4(aO2, 1, 0, 1);
        STAGE(0, 3, N2);
        MFMA16(aO1, bO0, 4);
        U_POST();
        // ---- ph7 ----
        U_PRE();
        LDA4(aO3, 1, 4, 1);
        STAGE(1, 0, P2);
        MFMA16(aO2, bO1, 0);
        U_POST();
        // ---- ph8 ----
        U_PRE();
        LDB4(bE0, 0, 0); LDA4(aE0, 0, 0, 0);
        STAGE(1, 1, P2);
        MFMA16(aO3, bO1, 4);
        U_POST();
    }
    asm volatile("s_waitcnt vmcnt(0) lgkmcnt(0)" ::: "memory");
    SBAR();
    __builtin_amdgcn_s_barrier();   // LDS now free for epilogue reuse

    // epilogue: C/D layout col = lane&15, row = (lane>>4)*4 + j
    if (COLSUM == 0) {
        // 1) acc -> LDS as one 256x256 bf16 tile ([row][512B], col-bytes XOR row-swizzled)
        char* slb = (char*)&lds[0][0][0][0];
        #pragma unroll
        for (int nf = 0; nf < 4; ++nf) {
            int ncol = wn * 64 + nf * 16 + (lane & 15);        // 0..255 in tile
            float bv = bias[n0 + ncol];
            #pragma unroll
            for (int mf = 0; mf < 8; ++mf) {
                int rbase = wm * 128 + mf * 16 + ((lane >> 4) << 2);
                #pragma unroll
                for (int j = 0; j < 4; ++j) {
                    int row = rbase + j;
                    float v = fmaxf(acc[mf][nf][j] + bv, 0.f);
                    int byte = row * 512 + ((ncol * 2) ^ ((row & 7) << 4));
                    *(unsigned short*)(slb + byte) = f2bf_rne(v);
                }
            }
        }
        __syncthreads();
        // 2) LDS -> global, wave-contiguous full 64B lines, nontemporal (L2 stays
        //    clean -> no kernel-boundary dirty writeback; H lands in memory-side L3).
        {
            int rsub = t >> 5;              // 0..15
            int cb = (t & 31) * 16;         // 0..496
            #pragma unroll
            for (int i2 = 0; i2 < 16; ++i2) {
                int row = i2 * 16 + rsub;
                const char* src = slb + row * 512 + (cb ^ ((row & 7) << 4));
                uint32x4 v = *(const uint32x4*)src;
                char* dst = (char*)Hout + ((size_t)(m0 + row) * HGDIM + n0) * 2 + cb;
                __builtin_nontemporal_store(v, (uint32x4*)dst);
            }
        }
    } else {
        #pragma unroll
        for (int nf = 0; nf < 4; ++nf) {
            int ncol = n0 + wn * 64 + nf * 16 + (lane & 15);
            float bv = bias[ncol];
            float cs = 0.f;
            #pragma unroll
            for (int mf = 0; mf < 8; ++mf) {
                long rbase = row0g + m0 + wm * 128 + mf * 16 + ((lane >> 4) << 2);
                #pragma unroll
                for (int j = 0; j < 4; ++j) {
                    float v = fmaxf(acc[mf][nf][j] + bv, 0.f);
                    if (rbase + j < nvalid) cs += v;
                }
            }
            cs += __shfl_xor(cs, 16);
            cs += __shfl_xor(cs, 32);
            if ((lane >> 4) == 0) atomicAdd(&emb[ncol], cs);
        }
    }
}

extern "C" void kernel_launch(void* const* d_in, const int* in_sizes, int n_in,
                              void* d_out, int out_size, void* d_ws, size_t ws_size,
                              hipStream_t stream) {
    const float* x   = (const float*)d_in[0];
    const float* q   = (const float*)d_in[1];
    const float* gW0 = (const float*)d_in[2];
    const float* gb0 = (const float*)d_in[3];
    const float* gW1 = (const float*)d_in[4];
    const float* gb1 = (const float*)d_in[5];
    const float* gW2 = (const float*)d_in[6];
    const float* gb2 = (const float*)d_in[7];
    const float* fW0 = (const float*)d_in[8];
    const float* fb0 = (const float*)d_in[9];
    const float* fW1 = (const float*)d_in[10];
    const float* fb1 = (const float*)d_in[11];
    const float* fW2 = (const float*)d_in[12];
    const float* fb2 = (const float*)d_in[13];
    float* out = (float*)d_out;

    char* ws = (char*)d_ws;
    size_t off = 0;
    auto alloc = [&](size_t bytes) -> char* {
        char* p = ws + off;
        off += (bytes + 255) & ~(size_t)255;
        return p;
    };
    unsigned short* xb  = (unsigned short*)alloc((NROWS + 1) * 256 * 2);  // +1 zero row
    unsigned short* w0t = (unsigned short*)alloc((size_t)1024 * 512 * 2);
    unsigned short* w1t = (unsigned short*)alloc((size_t)1024 * 1024 * 2);
    unsigned short* w2t = (unsigned short*)alloc((size_t)1024 * 1024 * 2);
    float* c0  = (float*)alloc(4096);
    float* emb = (float*)alloc(4096);
    float* e1  = (float*)alloc(4096);
    float* e2  = (float*)alloc(4096);
    size_t fixed = off;
    size_t avail = (ws_size > fixed) ? ws_size - fixed : 0;
    long CR = (long)((avail / 2) / (HGDIM * 2));
    CR = (CR / 512) * 512;              // keep mblocks even -> nwg % 8 == 0
    if (CR > NROWS) CR = NROWS;
    if (CR < 512) CR = 512;
    unsigned short* H0 = (unsigned short*)alloc((size_t)CR * HGDIM * 2);
    unsigned short* H1 = (unsigned short*)alloc((size_t)CR * HGDIM * 2);

    prep<<<dim3(NB_CVT + NB_T0 + NB_T1 + NB_T2 + NB_C0 + 1), 256, 0, stream>>>(
        x, xb, gW0, w0t, gW1, w1t, gW2, w2t, q, gb0, c0, emb, e1, e2, out);

    for (long r0 = 0; r0 < NROWS; r0 += CR) {
        long rows = NROWS - r0; if (rows > CR) rows = CR;
        int mblocks = (int)(rows / 256);
        dim3 g((unsigned)(mblocks * 4));
        // H0 = relu(x[:-1]*W0a + x[1:]*W0b + c0): A rows are overlapping 512-windows of xb
        gemmV<0><<<g, 512, 0, stream>>>(xb + r0 * 256, 256, w0t, 512, c0, 512,
                                        H0, nullptr, 0, 0, mblocks);
        gemmV<0><<<g, 512, 0, stream>>>(H0, 1024, w1t, 1024, gb1, 1024,
                                        H1, nullptr, 0, 0, mblocks);
        gemmV<1><<<g, 512, 0, stream>>>(H1, 1024, w2t, 1024, gb2, 1024,
                                        nullptr, emb, r0, NVALID, mblocks);
    }

    fc_partial<false><<<dim3(4, 8), 256, 0, stream>>>(emb, fW0, fb0, e1, 1024);
    fc_partial<true><<<dim3(2, 8), 256, 0, stream>>>(e1, fW1, fb1, e2, 512);
    fc_partial<true><<<dim3(1, 4), 256, 0, stream>>>(e2, fW2, fb2, out, 256);
}